// Round 11
// baseline (258.129 us; speedup 1.0000x reference)
//
#include <hip/hip_runtime.h>
#include <stdint.h>

#define MROWS 8192
#define NGT   8192
#define KC    8                    // global top-K per row (candidates for greedy)
#define KL    2                    // per-lane kept in fast path (certificate-verified)
#define RPL   4                    // rows per lane in greedy (256 rows/pass)
#define THRESH2_BITS 0x41C7FFFFu   // s_bits <  this  <=>  sqrt_rn(s) < 5.0f (exact)

// Squared distance, exact same fp32 ops/association as numpy pre-sqrt: diff, square,
// left-to-right sum. No FMA contraction. Ordering by (s,idx) == ordering by (d,idx)
// except on sqrt-rounding collisions (prob ~0; affected rows are masked or shift the
// scalar loss by ~4e-4 << 2.6e-2 threshold).
__device__ __forceinline__ unsigned dist2_bits(float px, float py, float pz,
                                               float gx, float gy, float gz) {
#pragma clang fp contract(off)
  float dx = px - gx;
  float dy = py - gy;
  float dz = pz - gz;
  float s = (dx * dx + dy * dy) + dz * dz;
  return __float_as_uint(s);  // s >= 0, bits order == float order
}

__device__ __forceinline__ unsigned long long wave_min64(unsigned long long v) {
#pragma unroll
  for (int off = 32; off >= 1; off >>= 1) {
    unsigned long long o = __shfl_xor(v, off, 64);
    v = (o < v) ? o : v;
  }
  return v;
}

template <int K>
__device__ __forceinline__ void insert_sorted(unsigned (&kd)[K], unsigned (&ki)[K],
                                              unsigned key, unsigned j) {
#pragma unroll
  for (int t = K - 1; t >= 1; --t) {
    bool a = key < kd[t];
    bool b = key < kd[t - 1];
    if (a) {
      if (b) { kd[t] = kd[t - 1]; ki[t] = ki[t - 1]; }
      else   { kd[t] = key;       ki[t] = j; }
    }
  }
  if (key < kd[0]) { kd[0] = key; ki[0] = j; }
}

// Extract the 8 lex-smallest (s,idx) keys from the union of per-lane sorted lists.
// Lane r ends holding the r-th smallest; e8 = 8th smallest key (all lanes).
template <int K>
__device__ __forceinline__ void extract8(unsigned (&kd)[K], unsigned (&ki)[K], int lane,
                                         unsigned& resd, unsigned& resi,
                                         unsigned long long& e8) {
#pragma unroll
  for (int rr = 0; rr < KC; ++rr) {
    unsigned long long head = ((unsigned long long)kd[0] << 32) | (unsigned long long)ki[0];
    unsigned long long m = wave_min64(head);
    if (head == m) {  // unique owner (idx unique) pops its head
#pragma unroll
      for (int t = 0; t < K - 1; ++t) { kd[t] = kd[t + 1]; ki[t] = ki[t + 1]; }
      kd[K - 1] = 0xFFFFFFFFu; ki[K - 1] = 0xFFFFFFFFu;
    }
    if (lane == rr) { resd = (unsigned)(m >> 32); resi = (unsigned)m; }
    e8 = m;
  }
}

// ---------------- Kernel 0: pack gt centers into L2-resident float4 SoA ----------------
__global__ __launch_bounds__(256) void pack_kernel(const float* __restrict__ gt,
                                                   float4* __restrict__ cen) {
  int j = blockIdx.x * 256 + threadIdx.x;
  if (j < NGT) cen[j] = make_float4(gt[j * 7 + 0], gt[j * 7 + 1], gt[j * 7 + 2], 0.0f);
}

// ---------------- Kernel A: top-8 per row, packed as (idx<<1)|claimable ---------------
// Per-lane top-2 + exactness certificate: every discard lex-exceeds the lane's final
// (kd[1],ki[1]) guard; if all guards >= e8, the extracted top-8 is exact. Certificate
// failures (~1.4% of rows) recompute with per-lane top-8 (unconditionally exact).
__global__ __launch_bounds__(256, 8) void topk_kernel(const float* __restrict__ pred,
                                                      const float4* __restrict__ cen,
                                                      unsigned* __restrict__ cand) {
  const int tid = threadIdx.x;
  const int lane = tid & 63;
  const int row = (blockIdx.x * 256 + tid) >> 6;  // 1 row per wave, grid 2048

  float px = pred[(size_t)row * 7 + 0];
  float py = pred[(size_t)row * 7 + 1];
  float pz = pred[(size_t)row * 7 + 2];

  unsigned kd[KL], ki[KL];
#pragma unroll
  for (int t = 0; t < KL; ++t) { kd[t] = 0xFFFFFFFFu; ki[t] = 0xFFFFFFFFu; }

#pragma unroll 2
  for (int j0 = 0; j0 < NGT / 64; ++j0) {
    int j = j0 * 64 + lane;            // coalesced; disjoint idx per lane
    float4 c = cen[j];
    unsigned key = dist2_bits(px, py, pz, c.x, c.y, c.z);
    if (key < kd[KL - 1]) insert_sorted<KL>(kd, ki, key, (unsigned)j);
  }

  unsigned long long guard =
      ((unsigned long long)kd[KL - 1] << 32) | (unsigned long long)ki[KL - 1];
  unsigned resd = 0, resi = 0;
  unsigned long long e8 = 0;
  extract8<KL>(kd, ki, lane, resd, resi, e8);

  if (__ballot(guard < e8) != 0ull) {
    // a lane may have discarded a true top-8 member -> exact recompute
    unsigned fd[KC], fi[KC];
#pragma unroll
    for (int t = 0; t < KC; ++t) { fd[t] = 0xFFFFFFFFu; fi[t] = 0xFFFFFFFFu; }
    for (int j0 = 0; j0 < NGT / 64; ++j0) {
      int j = j0 * 64 + lane;
      float4 c = cen[j];
      unsigned key = dist2_bits(px, py, pz, c.x, c.y, c.z);
      if (key < fd[KC - 1]) insert_sorted<KC>(fd, fi, key, (unsigned)j);
    }
    unsigned long long dummy;
    extract8<KC>(fd, fi, lane, resd, resi, dummy);
  }
  // packed candidate: idx in bits 31..1, claimable (d<5.0, exact bit bound) in bit 0
  if (lane < KC)
    cand[(size_t)row * KC + lane] = (resi << 1) | (resd < THRESH2_BITS ? 1u : 0u);
}

// ---------------- Kernel B: batched greedy, no-restart passes (1 wave) ----------------
// 256 rows/pass. Fixed point of {propose first remaining candidate -> atomicMin claim ->
// losers drop} == serial greedy by induction on row order (claims monotone). Exhausted
// rows are handled IN-PASS: commit prefix, full-scan fallback (avail is then serially
// correct), drop g* from remaining masks, resume. No pass restart, prefetch always hits.
// Stale claim slots of committed rows correctly block later proposers (their offset is
// strictly larger). Non-claimer staleness is loss-invariant (sorted candidates: once
// first-available has d>=5, all later do too; unmatched idx is masked out of the loss).
__global__ __launch_bounds__(64) void greedy_kernel(const unsigned* __restrict__ cand,
                                                    const float* __restrict__ pred,
                                                    const float4* __restrict__ cen,
                                                    unsigned* __restrict__ match) {
  __shared__ unsigned avail[NGT / 32];           // 1 KB bitmap
  __shared__ unsigned claim[NGT];                // 32 KB (reset after each pass)
  const int lane = threadIdx.x;

  for (int w = lane; w < NGT / 32; w += 64) avail[w] = 0xFFFFFFFFu;
  for (int j = lane; j < NGT; j += 64) claim[j] = 0xFFFFFFFFu;
  __syncthreads();

  unsigned ci_[RPL][KC], ni_[RPL][KC];
  bool first = true;

  for (int base = 0; base < MROWS; base += 64 * RPL) {
    const int nAct = 64 * RPL;  // MROWS % 256 == 0

    if (first) {
#pragma unroll
      for (int q = 0; q < RPL; ++q) {
        const uint4* cr = (const uint4*)(cand + (size_t)(base + lane + 64 * q) * KC);
        uint4 a = cr[0], b = cr[1];
        ci_[q][0] = a.x; ci_[q][1] = a.y; ci_[q][2] = a.z; ci_[q][3] = a.w;
        ci_[q][4] = b.x; ci_[q][5] = b.y; ci_[q][6] = b.z; ci_[q][7] = b.w;
      }
      first = false;
    } else {
#pragma unroll
      for (int q = 0; q < RPL; ++q)
#pragma unroll
        for (int t = 0; t < KC; ++t) ci_[q][t] = ni_[q][t];
    }
#pragma unroll
    for (int q = 0; q < RPL; ++q) {      // prefetch next pass (always correct now)
      int pr = base + nAct + lane + 64 * q;
      if (pr >= MROWS) pr = MROWS - 1;
      const uint4* cr = (const uint4*)(cand + (size_t)pr * KC);
      uint4 a = cr[0], b = cr[1];
      ni_[q][0] = a.x; ni_[q][1] = a.y; ni_[q][2] = a.z; ni_[q][3] = a.w;
      ni_[q][4] = b.x; ni_[q][5] = b.y; ni_[q][6] = b.z; ni_[q][7] = b.w;
    }

    // pass-start availability masks
    unsigned m[RPL];
#pragma unroll
    for (int q = 0; q < RPL; ++q) {
      unsigned mm = 0;
#pragma unroll
      for (int t = 0; t < KC; ++t) {
        unsigned g = ci_[q][t] >> 1;
        mm |= ((avail[g >> 5] >> (g & 31)) & 1u) << t;
      }
      m[q] = mm;
    }

    int floor_ = 0;
    unsigned pe[RPL];
    bool cl[RPL];
    int rounds = 0;

    while (true) {
      // ---- fixed-point resolution over uncommitted rows ----
      while (true) {
#pragma unroll
        for (int q = 0; q < RPL; ++q) {
          int o = lane + 64 * q;
          unsigned e = 0;
#pragma unroll
          for (int t = KC - 1; t >= 0; --t)
            if (m[q] & (1u << t)) e = ci_[q][t];
          pe[q] = e;
          cl[q] = (o >= floor_) && (m[q] != 0u) && (e & 1u);
        }
#pragma unroll
        for (int q = 0; q < RPL; ++q)
          if (cl[q]) atomicMin(&claim[pe[q] >> 1], (unsigned)(lane + 64 * q));
        __builtin_amdgcn_wave_barrier();
        bool any = false;
        bool lost[RPL];
#pragma unroll
        for (int q = 0; q < RPL; ++q) {
          lost[q] = cl[q] && (claim[pe[q] >> 1] < (unsigned)(lane + 64 * q));
          any |= lost[q];
        }
        if (__ballot(any) == 0ull) break;
#pragma unroll
        for (int q = 0; q < RPL; ++q)
          if (lost[q]) m[q] &= (m[q] - 1u);
        if (++rounds > 2100) {  // unreachable exact-safety: serialize the rest
#pragma unroll
          for (int q = 0; q < RPL; ++q)
            if (lane + 64 * q >= floor_) m[q] = 0u;
        }
      }

      // ---- first exhausted uncommitted row ----
      unsigned fe = 0xFFFFu;
#pragma unroll
      for (int q = 0; q < RPL; ++q) {
        unsigned o = (unsigned)(lane + 64 * q);
        if (o >= (unsigned)floor_ && m[q] == 0u && o < fe) fe = o;
      }
#pragma unroll
      for (int off = 32; off >= 1; off >>= 1) {
        unsigned o2 = __shfl_xor(fe, off, 64);
        fe = o2 < fe ? o2 : fe;
      }
      int feI = (fe == 0xFFFFu) ? nAct : (int)fe;

      // ---- commit rows [floor_, feI) ----
#pragma unroll
      for (int q = 0; q < RPL; ++q) {
        int o = lane + 64 * q;
        if (o >= floor_ && o < feI) {
          unsigned g = pe[q] >> 1;
          match[base + o] = (cl[q] ? 0x80000000u : 0u) | g;
          if (cl[q]) atomicAnd(&avail[g >> 5], ~(1u << (g & 31)));
        }
      }
      __builtin_amdgcn_wave_barrier();
      if (feI == nAct) break;  // pass complete

      // ---- in-pass fallback for row base+feI (avail is serially correct here) ----
      {
        const int r = base + feI;
        float fx = pred[(size_t)r * 7 + 0];
        float fy = pred[(size_t)r * 7 + 1];
        float fz = pred[(size_t)r * 7 + 2];
        unsigned long long best = ~0ull;
        for (int j0 = 0; j0 < NGT / 64; ++j0) {
          int j = j0 * 64 + lane;
          if ((avail[j >> 5] >> (j & 31)) & 1u) {
            float4 c = cen[j];
            unsigned sb = dist2_bits(fx, fy, fz, c.x, c.y, c.z);
            unsigned long long key = ((unsigned long long)sb << 32) | (unsigned)j;
            if (key < best) best = key;
          }
        }
        unsigned long long mm2 = wave_min64(best);
        unsigned gstar = 0xFFFFFFFFu;
        if (mm2 != ~0ull) {
          unsigned sb = (unsigned)(mm2 >> 32);
          unsigned j = (unsigned)mm2;
          bool ok = sb < THRESH2_BITS;
          if (lane == 0) {
            match[r] = (ok ? 0x80000000u : 0u) | j;
            if (ok) atomicAnd(&avail[j >> 5], ~(1u << (j & 31)));
          }
          if (ok) gstar = j;  // wave-uniform
        } else if (lane == 0) {
          match[r] = 0u;  // nothing available -> unmatched (masked; idx irrelevant)
        }
        __builtin_amdgcn_wave_barrier();
        // surgical mask update: g* is now taken; claimers of g* re-propose next rounds
        if (gstar != 0xFFFFFFFFu) {
#pragma unroll
          for (int q = 0; q < RPL; ++q)
#pragma unroll
            for (int t = 0; t < KC; ++t)
              if ((ci_[q][t] >> 1) == gstar) m[q] &= ~(1u << t);
        }
        floor_ = feI + 1;
        if (floor_ >= nAct) break;
      }
    }

    // reset every claim slot this pass may have touched
#pragma unroll
    for (int q = 0; q < RPL; ++q)
#pragma unroll
      for (int t = 0; t < KC; ++t) claim[ci_[q][t] >> 1] = 0xFFFFFFFFu;
    __builtin_amdgcn_wave_barrier();
  }
}

// ---------------- Kernel C: loss terms + reduction ----------------
__device__ __forceinline__ float smooth_l1(float x) {
  float a = fabsf(x);
  return (a < 1.0f) ? (0.5f * a * a) : (a - 0.5f);
}

__global__ __launch_bounds__(256) void loss_kernel(const float* __restrict__ pred,
                                                   const float* __restrict__ gt,
                                                   const unsigned* __restrict__ match,
                                                   float* __restrict__ acc) {
  int i = blockIdx.x * 256 + threadIdx.x;
  float vc = 0.f, vs = 0.f, vo = 0.f, vi = 0.f, vk = 0.f;
  if (i < MROWS) {
    unsigned r = match[i];
    if (r & 0x80000000u) {
      unsigned j = r & 0x7FFFFFFFu;
      float p[7], g[7];
#pragma unroll
      for (int t = 0; t < 7; ++t) { p[t] = pred[i * 7 + t]; g[t] = gt[j * 7 + t]; }
      vc = smooth_l1(p[0] - g[0]) + smooth_l1(p[1] - g[1]) + smooth_l1(p[2] - g[2]);
      vs = smooth_l1(p[3] - g[3]) + smooth_l1(p[4] - g[4]) + smooth_l1(p[5] - g[5]);
      float d = p[6] - g[6];
      float w = d - 6.283185307179586f * rintf(d * 0.15915494309189535f);
      vo = smooth_l1(w);
      float iw = fminf(p[0] + p[3] * 0.5f, g[0] + g[3] * 0.5f) -
                 fmaxf(p[0] - p[3] * 0.5f, g[0] - g[3] * 0.5f);
      iw = fmaxf(iw, 0.0f);
      float ih = fminf(p[1] + p[4] * 0.5f, g[1] + g[4] * 0.5f) -
                 fmaxf(p[1] - p[4] * 0.5f, g[1] - g[4] * 0.5f);
      ih = fmaxf(ih, 0.0f);
      float inter = iw * ih;
      float uni = p[3] * p[4] + g[3] * g[4] - inter;
      vi = 1.0f - inter / (uni + 1e-6f);
      vk = 1.0f;
    }
  }
#pragma unroll
  for (int off = 32; off >= 1; off >>= 1) {
    vc += __shfl_down(vc, off, 64);
    vs += __shfl_down(vs, off, 64);
    vo += __shfl_down(vo, off, 64);
    vi += __shfl_down(vi, off, 64);
    vk += __shfl_down(vk, off, 64);
  }
  if ((threadIdx.x & 63) == 0) {
    atomicAdd(&acc[0], vc);
    atomicAdd(&acc[1], vs);
    atomicAdd(&acc[2], vo);
    atomicAdd(&acc[3], vi);
    atomicAdd(&acc[4], vk);
  }
}

__global__ void finalize_kernel(const float* __restrict__ acc, float* __restrict__ out) {
  float k = fmaxf(acc[4], 1.0f);
  float loss = acc[0] / (3.0f * k)
             + 0.5f * (acc[1] / (3.0f * k) + acc[2] / k)
             + 2.0f * (acc[3] / k);
  out[0] = loss;
}

extern "C" void kernel_launch(void* const* d_in, const int* in_sizes, int n_in,
                              void* d_out, int out_size, void* d_ws, size_t ws_size,
                              hipStream_t stream) {
  const float* pred = (const float*)d_in[0];
  const float* gt   = (const float*)d_in[1];
  char* ws = (char*)d_ws;
  float* acc       = (float*)ws;                        // 32 B accumulators
  unsigned* match  = (unsigned*)(ws + 1024);            // 32 KB
  unsigned* cand   = (unsigned*)(ws + 33792);           // 256 KB packed candidates
  float4* cen      = (float4*)(ws + 295936);            // 128 KB packed centers

  hipMemsetAsync(acc, 0, 32, stream);
  pack_kernel<<<NGT / 256, 256, 0, stream>>>(gt, cen);
  topk_kernel<<<MROWS / 4, 256, 0, stream>>>(pred, cen, cand);
  greedy_kernel<<<1, 64, 0, stream>>>(cand, pred, cen, match);
  loss_kernel<<<MROWS / 256, 256, 0, stream>>>(pred, gt, match, acc);
  finalize_kernel<<<1, 1, 0, stream>>>(acc, (float*)d_out);
}